// Round 1
// baseline (2131.991 us; speedup 1.0000x reference)
//
#include <hip/hip_runtime.h>

// LSTM: BS=512, T=2048, IN=64, HS=128. Batch rows are independent ->
// 128 blocks x 4 rows, persistent t-loop per block, weights in registers,
// bf16 MFMA for gates, fp32 cell state.

#define T_STEPS 2048
#define IN_DIM 64
#define HS 128
#define NG 512          // 4*HS gate columns
#define ROWS 4          // batch rows per block
#define NBLK 128        // 512 / ROWS
#define NTHR 512        // 8 waves
#define ASTR 200        // shorts per A-row (192 + 8 pad -> bank-conflict-free-ish)
#define AROWS 16

typedef float f32x4 __attribute__((ext_vector_type(4)));
typedef short s16x8 __attribute__((ext_vector_type(8)));

__device__ __forceinline__ unsigned short f2bf(float f) {
  unsigned u = __float_as_uint(f);
  return (unsigned short)((u + 0x7fffu + ((u >> 16) & 1u)) >> 16);  // RNE
}
__device__ __forceinline__ float sigm(float x) {
  return 1.0f / (1.0f + __expf(-x));
}
__device__ __forceinline__ float tanhfast(float x) {
  // tanh(x) = 1 - 2/(e^{2x}+1); saturates correctly for |x| large
  return 1.0f - 2.0f / (__expf(2.0f * x) + 1.0f);
}

__global__ __launch_bounds__(NTHR, 2)
void lstm_kernel(const float* __restrict__ X, const float* __restrict__ W,
                 const float* __restrict__ U, const float* __restrict__ B,
                 const float* __restrict__ LW, const float* __restrict__ LB,
                 float* __restrict__ OUT) {
  __shared__ __align__(16) short Alds[AROWS * ASTR];  // [h(128) | x(64)] bf16, rows 4..15 zero
  __shared__ float Gl[ROWS * NG];                     // raw gates fp32

  const int tid  = threadIdx.x;
  const int lane = tid & 63;
  const int w    = tid >> 6;      // wave 0..7
  const int wb   = w * 64;        // this wave's gate-column base
  const int blk  = blockIdx.x;

  // ---- persistent weight fragments: wave w owns gate cols [wb, wb+64) ----
  // B-frag layout for mfma_f32_16x16x32_bf16: lane holds B[k][col],
  // col = lane&15 (+16*n), k = kt*32 + 8*(lane>>4) + j
  s16x8 bfr[4][6];
#pragma unroll
  for (int n = 0; n < 4; ++n) {
    const int col = wb + n * 16 + (lane & 15);
#pragma unroll
    for (int kt = 0; kt < 6; ++kt) {
#pragma unroll
      for (int j = 0; j < 8; ++j) {
        const int k = kt * 32 + ((lane >> 4) << 3) + j;
        const float v = (k < HS) ? U[k * NG + col] : W[(k - HS) * NG + col];
        bfr[n][kt][j] = (short)f2bf(v);
      }
    }
  }
  float biasr[4];
#pragma unroll
  for (int n = 0; n < 4; ++n) biasr[n] = B[wb + n * 16 + (lane & 15)];

  const float lwv = LW[tid & 127];
  const float lb  = LB[0];

  // ---- init A buffer (zeros rows 4..15 forever) ----
  for (int i = tid; i < AROWS * ASTR; i += NTHR) Alds[i] = 0;
  __syncthreads();

  // x prefetch: threads 0..255 each own (row r2, feature k2)
  const int r2 = (tid >> 6) & 3;
  const int k2 = tid & 63;
  float xcur = 0.f, xnext = 0.f;
  if (tid < 256) {
    const float* xp = X + ((long)(blk * ROWS + r2) * T_STEPS) * IN_DIM + k2;
    Alds[r2 * ASTR + HS + k2] = (short)f2bf(xp[0]);  // x(0)
    xcur  = xp[IN_DIM];                              // x(1)
    xnext = xp[2 * IN_DIM];                          // x(2)
  }
  __syncthreads();

  // A-frag: lane holds A[row][k], row = lane&15, k = kt*32 + 8*(lane>>4) + j
  s16x8 afr[6];
#pragma unroll
  for (int kt = 0; kt < 6; ++kt)
    afr[kt] = *(const s16x8*)&Alds[(lane & 15) * ASTR + kt * 32 + ((lane >> 4) << 3)];

  float creg = 0.f;                 // c[er][ej], persistent
  const int er = tid >> 7;          // 0..3
  const int ej = tid & 127;         // h column

#pragma unroll 1
  for (int t = 0; t < T_STEPS; ++t) {
    // gates = bias + [h|x] @ [U;W]
    f32x4 acc[4];
#pragma unroll
    for (int n = 0; n < 4; ++n) {
      acc[n][0] = biasr[n]; acc[n][1] = biasr[n];
      acc[n][2] = biasr[n]; acc[n][3] = biasr[n];
    }
#pragma unroll
    for (int kt = 0; kt < 6; ++kt)
#pragma unroll
      for (int n = 0; n < 4; ++n)
        acc[n] = __builtin_amdgcn_mfma_f32_16x16x32_bf16(afr[kt], bfr[n][kt], acc[n], 0, 0, 0);

    // D layout: col = lane&15, row = 4*(lane>>4)+r  -> lanes 0..15 hold real rows 0..3
    if (lane < 16) {
#pragma unroll
      for (int n = 0; n < 4; ++n)
#pragma unroll
        for (int r = 0; r < 4; ++r)
          Gl[r * NG + wb + n * 16 + lane] = acc[n][r];
    }
    __syncthreads();

    // dense elementwise cell update: one (row, h-col) per thread
    const float gi = Gl[er * NG + ej];
    const float gf = Gl[er * NG + HS + ej];
    const float gg = Gl[er * NG + 2 * HS + ej];
    const float go = Gl[er * NG + 3 * HS + ej];
    const float iv = sigm(gi), fv = sigm(gf), gv = tanhfast(gg), ov = sigm(go);
    creg = fv * creg + iv * gv;
    const float hv = ov * tanhfast(creg);

    if (t < T_STEPS - 1) {
      Alds[er * ASTR + ej] = (short)f2bf(hv);
      if (tid < 256) {
        Alds[r2 * ASTR + HS + k2] = (short)f2bf(xcur);  // x(t+1)
        xcur  = xnext;
        xnext = (t + 3 < T_STEPS)
              ? X[((long)(blk * ROWS + r2) * T_STEPS + (t + 3)) * IN_DIM + k2] : 0.f;
      }
    } else {
      // final step: write h, c; stage y partial products
      const int row = blk * ROWS + er;
      OUT[512 + row * HS + ej]   = hv;     // h_t
      OUT[66048 + row * HS + ej] = creg;   // c_t (512 + 512*128)
      Gl[er * NG + ej] = lwv * hv;         // safe: col ej<128 only read by this thread
    }
    __syncthreads();

    if (t < T_STEPS - 1) {
#pragma unroll
      for (int kt = 0; kt < 6; ++kt)
        afr[kt] = *(const s16x8*)&Alds[(lane & 15) * ASTR + kt * 32 + ((lane >> 4) << 3)];
    }
  }

  // y = h @ linear_w.T + b  (once, tiny)
  if (tid < ROWS) {
    float s = lb;
    for (int j = 0; j < HS; ++j) s += Gl[tid * NG + j];
    OUT[blk * ROWS + tid] = s;
  }
}

extern "C" void kernel_launch(void* const* d_in, const int* in_sizes, int n_in,
                              void* d_out, int out_size, void* d_ws, size_t ws_size,
                              hipStream_t stream) {
  const float* X  = (const float*)d_in[0];
  const float* W  = (const float*)d_in[1];
  const float* U  = (const float*)d_in[2];
  const float* B  = (const float*)d_in[3];
  const float* LW = (const float*)d_in[4];
  const float* LB = (const float*)d_in[5];
  lstm_kernel<<<dim3(NBLK), dim3(NTHR), 0, stream>>>(X, W, U, B, LW, LB, (float*)d_out);
}

// Round 2
// 1873.380 us; speedup vs baseline: 1.1380x; 1.1380x over previous
//
#include <hip/hip_runtime.h>

// LSTM BS=512, T=2048, IN=64, HS=128.
// 256 blocks x 2 batch rows (all CUs), 8 waves/block, persistent t-loop.
// Weights register-resident (bf16), gates via mfma_f32_16x16x32_bf16 with a
// slim 2-real-row A; h through a 2x128 bf16 LDS buffer, x prefetched 3 steps
// ahead through a tiny double-buffered LDS slot. fp32 cell state.

#define T_STEPS 2048
#define IN_DIM 64
#define HS 128
#define NG 512
#define ROWS 2
#define NBLK 256
#define NTHR 512
#define HSTR 136   // shorts per h row (128 + 8 pad, keeps 16B alignment)

typedef float f32x4 __attribute__((ext_vector_type(4)));
typedef float f32x2 __attribute__((ext_vector_type(2)));
typedef short s16x8 __attribute__((ext_vector_type(8)));

__device__ __forceinline__ unsigned short f2bf(float f) {
  unsigned u = __float_as_uint(f);
  return (unsigned short)((u + 0x7fffu + ((u >> 16) & 1u)) >> 16);  // RNE
}
__device__ __forceinline__ float sigm(float x) { return 1.0f / (1.0f + __expf(-x)); }
__device__ __forceinline__ float tanhfast(float x) {
  return 1.0f - 2.0f / (__expf(2.0f * x) + 1.0f);  // exact at +-inf
}

// gate buffer index: [col][row] with per-16-col pad (keeps b64 align, spreads banks)
__device__ __forceinline__ int gidx(int c) { return c * 2 + ((c >> 4) << 1); }

__global__ __launch_bounds__(NTHR, 2)
void lstm_kernel(const float* __restrict__ X, const float* __restrict__ W,
                 const float* __restrict__ U, const float* __restrict__ B,
                 const float* __restrict__ LW, const float* __restrict__ LB,
                 float* __restrict__ OUT) {
  __shared__ __align__(16) short Hlds[ROWS * HSTR];     // h(t+1), bf16
  __shared__ __align__(16) float Xl[2][ROWS][IN_DIM];   // x slots, parity (t)&1
  __shared__ __align__(16) float Gl2[1088];             // raw gates [col][row]+pad
  __shared__ float Ys[256];
  __shared__ float Ps[8];

  const int tid  = threadIdx.x;
  const int lane = tid & 63;
  const int w    = tid >> 6;      // wave 0..7
  const int wb   = w * 64;        // wave's gate-column base
  const int blk  = blockIdx.x;
  const int lrow = lane & 15;     // fragment row
  const int lg   = lane >> 4;     // fragment k-group

  // ---- persistent weight fragments (wave w owns gate cols [wb, wb+64)) ----
  // B-frag for mfma_f32_16x16x32_bf16: lane holds B[k][col], col=lane&15 (+16n),
  // k = kt*32 + 8*(lane>>4) + j.  K-order: [h(128) | x(64)] -> U then W.
  s16x8 bfr[4][6];
#pragma unroll
  for (int n = 0; n < 4; ++n) {
    const int col = wb + n * 16 + lrow;
#pragma unroll
    for (int kt = 0; kt < 6; ++kt) {
#pragma unroll
      for (int j = 0; j < 8; ++j) {
        const int k = kt * 32 + (lg << 3) + j;
        const float v = (k < HS) ? U[k * NG + col] : W[(k - HS) * NG + col];
        bfr[n][kt][j] = (short)f2bf(v);
      }
    }
  }

  // ---- elementwise-thread constants (tid<256: one (row er, h-col ej) each) ----
  const int er = tid >> 7;        // 0..1
  const int ej = tid & 127;
  float b0 = 0, b1 = 0, b2 = 0, b3 = 0;
  int i0 = 0, i1 = 0, i2 = 0, i3 = 0;
  if (tid < 256) {
    b0 = B[ej]; b1 = B[HS + ej]; b2 = B[2 * HS + ej]; b3 = B[3 * HS + ej];
    i0 = gidx(ej) + er;           i1 = gidx(HS + ej) + er;
    i2 = gidx(2 * HS + ej) + er;  i3 = gidx(3 * HS + ej) + er;
  }

  // ---- x prefetch pipeline (waves 0,1 own batch row = w) ----
  float xa = 0.f, xb = 0.f;
  const float* xg = nullptr;
  if (w < ROWS) {
    xg = X + ((long)(blk * ROWS + w) * T_STEPS) * IN_DIM + lane;
    const float x0 = xg[0];
    xa = xg[IN_DIM];          // x(1) -> written at t=0
    xb = xg[2 * IN_DIM];      // x(2) -> written at t=1
    Xl[0][w][lane] = x0;      // slot 0 = x(0)
  }
  for (int i = tid; i < ROWS * HSTR; i += NTHR) Hlds[i] = 0;  // h(0)=0
  __syncthreads();

  // ---- fragment registers ----
  s16x8 afr[6];
  const s16x8 zer = {0, 0, 0, 0, 0, 0, 0, 0};
#pragma unroll
  for (int kt = 0; kt < 6; ++kt) afr[kt] = zer;

  // build x-fragments for step t from slot (t&1); only rows 0,1 live
  auto buildx = [&](int slot) {
    if (lrow < ROWS) {
      const float* bp = &Xl[slot][lrow][lg << 3];
      const f32x4 a0 = *(const f32x4*)bp;
      const f32x4 a1 = *(const f32x4*)(bp + 4);
      const f32x4 c0 = *(const f32x4*)(bp + 32);
      const f32x4 c1 = *(const f32x4*)(bp + 36);
      s16x8 v0, v1;
#pragma unroll
      for (int j = 0; j < 4; ++j) {
        v0[j] = (short)f2bf(a0[j]); v0[4 + j] = (short)f2bf(a1[j]);
        v1[j] = (short)f2bf(c0[j]); v1[4 + j] = (short)f2bf(c1[j]);
      }
      afr[4] = v0; afr[5] = v1;
    }
  };
  buildx(0);

  float creg = 0.f, hreg = 0.f;

#pragma unroll 1
  for (int t = 0; t < T_STEPS; ++t) {
    // -- phase A --------------------------------------------------------
    if (w < ROWS) {
      // stage x(t+1) into slot (t+1)&1 (value was loaded ~2 steps ago)
      Xl[(t + 1) & 1][w][lane] = xa;
      xa = xb;
      const int tsrc = (t + 3 < T_STEPS) ? t + 3 : T_STEPS - 1;
      xb = xg[(long)tsrc * IN_DIM];   // issue load x(t+3)
    }

    f32x4 acc[4];
#pragma unroll
    for (int n = 0; n < 4; ++n) acc[n] = (f32x4){0.f, 0.f, 0.f, 0.f};
    // x-fragments first (ready), h-fragment ds_reads still landing
    const int kord[6] = {4, 5, 0, 1, 2, 3};
#pragma unroll
    for (int kk = 0; kk < 6; ++kk) {
      const int kt = kord[kk];
#pragma unroll
      for (int n = 0; n < 4; ++n)
        acc[n] = __builtin_amdgcn_mfma_f32_16x16x32_bf16(afr[kt], bfr[n][kt], acc[n], 0, 0, 0);
    }

    // D layout: col=lane&15, row=reg (lanes 0-15 hold real rows 0,1)
    if (lane < 16) {
#pragma unroll
      for (int n = 0; n < 4; ++n) {
        const int col = wb + n * 16 + lane;
        f32x2 v; v[0] = acc[n][0]; v[1] = acc[n][1];
        *(f32x2*)&Gl2[gidx(col)] = v;
      }
    }
    __syncthreads();

    // -- phase B --------------------------------------------------------
    if (tid < 256) {
      const float gi = Gl2[i0] + b0;
      const float gf = Gl2[i1] + b1;
      const float gg = Gl2[i2] + b2;
      const float go = Gl2[i3] + b3;
      const float iv = sigm(gi), fv = sigm(gf), gv = tanhfast(gg), ov = sigm(go);
      creg = fv * creg + iv * gv;
      hreg = ov * tanhfast(creg);
      if (t < T_STEPS - 1) {
        Hlds[er * HSTR + ej] = (short)f2bf(hreg);
      } else {
        const int row = blk * ROWS + er;
        OUT[512 + row * HS + ej]   = hreg;   // h_t
        OUT[66048 + row * HS + ej] = creg;   // c_t
      }
    }
    buildx((t + 1) & 1);          // x-fragments for step t+1 (all waves)
    __syncthreads();

    if (t < T_STEPS - 1) {
      if (lrow < ROWS) {          // h-fragments for step t+1 (8 lanes/wave)
#pragma unroll
        for (int kt = 0; kt < 4; ++kt)
          afr[kt] = *(const s16x8*)&Hlds[lrow * HSTR + kt * 32 + (lg << 3)];
      }
    }
  }

  // ---- y = h @ linear_w.T + b ----
  if (tid < 256) Ys[tid] = LW[ej] * hreg;
  __syncthreads();
  if (tid < 8) {
    const int r = tid >> 2, seg = tid & 3;
    float s = 0.f;
#pragma unroll 8
    for (int j = 0; j < 32; ++j) s += Ys[r * 128 + seg * 32 + j];
    Ps[tid] = s;
  }
  __syncthreads();
  if (tid < ROWS) {
    OUT[blk * ROWS + tid] = LB[0] + Ps[tid * 4] + Ps[tid * 4 + 1] + Ps[tid * 4 + 2] + Ps[tid * 4 + 3];
  }
}

extern "C" void kernel_launch(void* const* d_in, const int* in_sizes, int n_in,
                              void* d_out, int out_size, void* d_ws, size_t ws_size,
                              hipStream_t stream) {
  const float* X  = (const float*)d_in[0];
  const float* W  = (const float*)d_in[1];
  const float* U  = (const float*)d_in[2];
  const float* B  = (const float*)d_in[3];
  const float* LW = (const float*)d_in[4];
  const float* LB = (const float*)d_in[5];
  lstm_kernel<<<dim3(NBLK), dim3(NTHR), 0, stream>>>(X, W, U, B, LW, LB, (float*)d_out);
}

// Round 3
// 1631.945 us; speedup vs baseline: 1.3064x; 1.1479x over previous
//
#include <hip/hip_runtime.h>

// LSTM BS=512, T=2048, IN=64, HS=128.
// 256 blocks x 2 batch rows, 8 waves, persistent t-loop.
// Wave w owns cols [16w,16w+16) of EACH gate (n-tile n = gate n), so the
// cell update is fully in-register (ds_swizzle xor-16 spreads row1 to
// lanes 16-31). Only h crosses waves: double-buffered 2x128 bf16 LDS,
// ONE barrier per step. Weights bf16 register-resident; fp32 cell state.

#define T_STEPS 2048
#define IN_DIM 64
#define HS 128
#define NG 512
#define ROWS 2
#define NBLK 256
#define NTHR 512
#define HSTR 144   // shorts per h row: 288B -> row1 banks shifted by 8 (no 4-way)

typedef float f32x4 __attribute__((ext_vector_type(4)));
typedef short s16x8 __attribute__((ext_vector_type(8)));

__device__ __forceinline__ unsigned short f2bf(float f) {
  unsigned u = __float_as_uint(f);
  return (unsigned short)((u + 0x7fffu + ((u >> 16) & 1u)) >> 16);  // RNE
}
__device__ __forceinline__ float rcpf(float x) { return __builtin_amdgcn_rcpf(x); }
__device__ __forceinline__ float sigm(float x) { return rcpf(1.0f + __expf(-x)); }
__device__ __forceinline__ float tanhfast(float x) {
  return 1.0f - 2.0f * rcpf(__expf(2.0f * x) + 1.0f);  // exact at +-inf
}

__global__ __launch_bounds__(NTHR, 2)
void lstm_kernel(const float* __restrict__ X, const float* __restrict__ W,
                 const float* __restrict__ U, const float* __restrict__ B,
                 const float* __restrict__ LW, const float* __restrict__ LB,
                 float* __restrict__ OUT) {
  __shared__ __align__(16) short Hb[2][ROWS * HSTR];   // h(t) bf16, parity t&1
  __shared__ __align__(16) short Xs[2][ROWS][IN_DIM];  // x(t) bf16, parity t&1
  __shared__ float Ys[256];
  __shared__ float Ps[8];

  const int tid  = threadIdx.x;
  const int lane = tid & 63;
  const int w    = tid >> 6;      // wave 0..7
  const int blk  = blockIdx.x;
  const int lrow = lane & 15;
  const int lg   = lane >> 4;

  // ---- weights: bfr[n][kt] covers gate n, cols n*128 + 16w + [0,16) ----
  // B-frag (mfma_f32_16x16x32_bf16): col = lane&15, k = kt*32 + 8*(lane>>4)+j
  s16x8 bfr[4][6];
#pragma unroll
  for (int n = 0; n < 4; ++n) {
    const int col = n * HS + w * 16 + lrow;
#pragma unroll
    for (int kt = 0; kt < 6; ++kt) {
#pragma unroll
      for (int j = 0; j < 8; ++j) {
        const int k = kt * 32 + (lg << 3) + j;
        const float v = (k < HS) ? U[k * NG + col] : W[(k - HS) * NG + col];
        bfr[n][kt][j] = (short)f2bf(v);
      }
    }
  }
  float biasr[4];
#pragma unroll
  for (int n = 0; n < 4; ++n) biasr[n] = B[n * HS + w * 16 + lrow];

  // ---- x prefetch pipeline (waves 0,1 own batch row = w) ----
  float xa = 0.f, xb = 0.f;
  const float* xg = nullptr;
  if (w < ROWS) {
    xg = X + ((long)(blk * ROWS + w) * T_STEPS) * IN_DIM + lane;
    Xs[0][w][lane] = (short)f2bf(xg[0]);   // x(0)
    xa = xg[IN_DIM];                        // x(1)
    xb = xg[2 * IN_DIM];                    // x(2)
  }
  __syncthreads();

  // ---- A fragments: row = lane&15 (rows 0,1 real), k = kt*32+8*lg+j ----
  s16x8 afr[6];
  const s16x8 zer = {0, 0, 0, 0, 0, 0, 0, 0};
#pragma unroll
  for (int kt = 0; kt < 4; ++kt) afr[kt] = zer;   // h(0) = 0
  afr[4] = zer; afr[5] = zer;
  if (lrow < ROWS) {
    afr[4] = *(const s16x8*)&Xs[0][lrow][lg << 3];
    afr[5] = *(const s16x8*)&Xs[0][lrow][32 + (lg << 3)];
  }

  float creg = 0.f;

#pragma unroll 1
  for (int t = 0; t < T_STEPS; ++t) {
    // stage x(t+1) (loaded 2 steps ago), issue load x(t+3)
    if (w < ROWS) {
      Xs[(t + 1) & 1][w][lane] = (short)f2bf(xa);
      xa = xb;
      const int tsrc = (t + 3 < T_STEPS) ? t + 3 : T_STEPS - 1;
      xb = xg[(long)tsrc * IN_DIM];
    }

    // gates = bias + [h|x] @ [U;W]   (x-tiles first: their reads land first)
    f32x4 acc[4];
#pragma unroll
    for (int n = 0; n < 4; ++n) {
      acc[n][0] = biasr[n]; acc[n][1] = biasr[n];
      acc[n][2] = biasr[n]; acc[n][3] = biasr[n];
    }
    const int kord[6] = {4, 5, 0, 1, 2, 3};
#pragma unroll
    for (int kk = 0; kk < 6; ++kk) {
      const int kt = kord[kk];
#pragma unroll
      for (int n = 0; n < 4; ++n)
        acc[n] = __builtin_amdgcn_mfma_f32_16x16x32_bf16(afr[kt], bfr[n][kt], acc[n], 0, 0, 0);
    }

    // in-register gate combine: lane L<16 has (row0,row1) in regs 0,1 of each
    // acc[n]; swizzle xor-16 hands row1 to lanes 16..31 (one row per lane).
    float v[4];
#pragma unroll
    for (int n = 0; n < 4; ++n) {
      const float s = __int_as_float(
          __builtin_amdgcn_ds_swizzle(__float_as_int(acc[n][1]), 0x401F));
      v[n] = (lane & 16) ? s : acc[n][0];
    }
    const float iv = sigm(v[0]), fv = sigm(v[1]);
    const float gv = tanhfast(v[2]), ov = sigm(v[3]);
    creg = fv * creg + iv * gv;
    const float hv = ov * tanhfast(creg);

    if (lane < 32) {
      const int col = w * 16 + lrow;
      const int r   = lg & 1;
      if (t < T_STEPS - 1) {
        Hb[(t + 1) & 1][r * HSTR + col] = (short)f2bf(hv);
      } else {
        const int row = blk * ROWS + r;
        OUT[512 + row * HS + col]   = hv;    // h_t
        OUT[66048 + row * HS + col] = creg;  // c_t
        Ys[r * HS + col] = LW[col] * hv;     // y partial
      }
    }
    __syncthreads();

    if (t < T_STEPS - 1) {
      if (lrow < ROWS) {
        const int p = (t + 1) & 1;
        afr[4] = *(const s16x8*)&Xs[p][lrow][lg << 3];
        afr[5] = *(const s16x8*)&Xs[p][lrow][32 + (lg << 3)];
        const short* hb = &Hb[p][lrow * HSTR];
        afr[0] = *(const s16x8*)&hb[(lg << 3)];
        afr[1] = *(const s16x8*)&hb[32 + (lg << 3)];
        afr[2] = *(const s16x8*)&hb[64 + (lg << 3)];
        afr[3] = *(const s16x8*)&hb[96 + (lg << 3)];
      }
    }
  }

  // ---- y = h @ linear_w.T + b (once) ----
  if (tid < 8) {
    const int r = tid >> 2, seg = tid & 3;
    float s = 0.f;
#pragma unroll 8
    for (int j = 0; j < 32; ++j) s += Ys[r * 128 + seg * 32 + j];
    Ps[tid] = s;
  }
  __syncthreads();
  if (tid < ROWS) {
    OUT[blk * ROWS + tid] = LB[0] + Ps[tid * 4] + Ps[tid * 4 + 1]
                                  + Ps[tid * 4 + 2] + Ps[tid * 4 + 3];
  }
}

extern "C" void kernel_launch(void* const* d_in, const int* in_sizes, int n_in,
                              void* d_out, int out_size, void* d_ws, size_t ws_size,
                              hipStream_t stream) {
  const float* X  = (const float*)d_in[0];
  const float* W  = (const float*)d_in[1];
  const float* U  = (const float*)d_in[2];
  const float* B  = (const float*)d_in[3];
  const float* LW = (const float*)d_in[4];
  const float* LB = (const float*)d_in[5];
  lstm_kernel<<<dim3(NBLK), dim3(NTHR), 0, stream>>>(X, W, U, B, LW, LB, (float*)d_out);
}

// Round 4
// 1389.976 us; speedup vs baseline: 1.5338x; 1.1741x over previous
//
#include <hip/hip_runtime.h>

// LSTM BS=512, T=2048, IN=64, HS=128.
// Phase 1 (zgemm): Z[b][t][:] = x[b][t]@W + bias, dense full-row MFMA GEMM,
//   stored bf16 in scan-native packed chunks of 8 shorts (4 gates x 2 rows).
// Phase 2 (scan): 256 blocks x 2 rows, 8 waves; per step only K=128 (U*h):
//   16 MFMAs, acc initialized straight from a prefetched Z chunk.
// Fallback (ws too small): R3 kernel with in-loop x@W (K=192).

#define T_STEPS 2048
#define IN_DIM 64
#define HS 128
#define NG 512
#define ROWS 2
#define NBLK 256
#define NTHR 512
#define HSTR 144

typedef float f32x4 __attribute__((ext_vector_type(4)));
typedef short s16x8 __attribute__((ext_vector_type(8)));

__device__ __forceinline__ unsigned short f2bf(float f) {
  unsigned u = __float_as_uint(f);
  return (unsigned short)((u + 0x7fffu + ((u >> 16) & 1u)) >> 16);  // RNE
}
__device__ __forceinline__ float bf2f(unsigned short s) {
  return __int_as_float(((int)s) << 16);
}
__device__ __forceinline__ float rcpf(float x) { return __builtin_amdgcn_rcpf(x); }
__device__ __forceinline__ float sigm(float x) { return rcpf(1.0f + __expf(-x)); }
__device__ __forceinline__ float tanhfast(float x) {
  return 1.0f - 2.0f * rcpf(__expf(2.0f * x) + 1.0f);
}

// ---------------------------------------------------------------------------
// Phase 1: Z = x@W + bias.  256 persistent blocks (1/CU), 256 thr (4 waves).
// Block bp owns batch rows {2bp, 2bp+1}; iterates 256 tiles of 8 timesteps.
// A-tile rows: row = 2*tloc + r  (tloc=t&7, r=b&1) -> 16 real rows per MFMA.
// Chunk layout: Zp[((b>>1)*2048+t)*128 + c]*8 shorts, c=0..127 scan col,
//   shorts[n*2+r] = Z[b=2bp+r][t][n*128 + c].
// ---------------------------------------------------------------------------
__global__ __launch_bounds__(256, 1)
void zgemm_kernel(const float* __restrict__ X, const float* __restrict__ W,
                  const float* __restrict__ B, unsigned short* __restrict__ Zp) {
  __shared__ __align__(16) unsigned short Wl[NG * IN_DIM];   // [col][k] bf16, 64KB
  __shared__ __align__(16) unsigned short Zl[8 * 128 * 8];   // 16KB repack buf

  const int tid  = threadIdx.x;
  const int lane = tid & 63;
  const int w    = tid >> 6;     // wave 0..3: cols [128w, 128w+128)
  const int lrow = lane & 15;
  const int lg   = lane >> 4;
  const int bp   = blockIdx.x;

  // stage W transposed to [col][k] bf16 (reads coalesced over col)
  for (int idx = tid; idx < IN_DIM * NG; idx += 256) {
    const int k = idx >> 9, c = idx & 511;
    Wl[c * IN_DIM + k] = f2bf(W[idx]);
  }
  __syncthreads();

  // persistent B-frags + bias
  s16x8 bfrp[8][2];
#pragma unroll
  for (int n = 0; n < 8; ++n)
#pragma unroll
    for (int kt = 0; kt < 2; ++kt)
      bfrp[n][kt] = *(const s16x8*)&Wl[(w * 128 + n * 16 + lrow) * IN_DIM + kt * 32 + (lg << 3)];
  float biasv[8];
#pragma unroll
  for (int n = 0; n < 8; ++n) biasv[n] = B[w * 128 + n * 16 + lrow];

  // A source: lane's row -> b = 2bp + (lrow&1), tloc = lrow>>1, k = 8lg+...
  const float* xbase = X + ((long)(2 * bp + (lrow & 1)) * T_STEPS + (lrow >> 1)) * IN_DIM + (lg << 3);

  f32x4 xf0, xf1, xf2, xf3;
  xf0 = *(const f32x4*)(xbase);
  xf1 = *(const f32x4*)(xbase + 4);
  xf2 = *(const f32x4*)(xbase + 32);
  xf3 = *(const f32x4*)(xbase + 36);

#pragma unroll 1
  for (int tc = 0; tc < 256; ++tc) {
    s16x8 a0, a1;
#pragma unroll
    for (int j = 0; j < 4; ++j) {
      a0[j] = (short)f2bf(xf0[j]); a0[4 + j] = (short)f2bf(xf1[j]);
      a1[j] = (short)f2bf(xf2[j]); a1[4 + j] = (short)f2bf(xf3[j]);
    }
    if (tc < 255) {  // prefetch next tile's A
      const float* p = xbase + (long)(tc + 1) * 8 * IN_DIM;
      xf0 = *(const f32x4*)(p);
      xf1 = *(const f32x4*)(p + 4);
      xf2 = *(const f32x4*)(p + 32);
      xf3 = *(const f32x4*)(p + 36);
    }

    f32x4 acc[8];
#pragma unroll
    for (int n = 0; n < 8; ++n) {
      acc[n][0] = biasv[n]; acc[n][1] = biasv[n];
      acc[n][2] = biasv[n]; acc[n][3] = biasv[n];
    }
#pragma unroll
    for (int n = 0; n < 8; ++n)
      acc[n] = __builtin_amdgcn_mfma_f32_16x16x32_bf16(a0, bfrp[n][0], acc[n], 0, 0, 0);
#pragma unroll
    for (int n = 0; n < 8; ++n)
      acc[n] = __builtin_amdgcn_mfma_f32_16x16x32_bf16(a1, bfrp[n][1], acc[n], 0, 0, 0);

    // repack into chunk layout: D row = 4*lg + rr -> (tloc, r)
#pragma unroll
    for (int n = 0; n < 8; ++n)
#pragma unroll
      for (int rr = 0; rr < 4; ++rr) {
        const int row  = 4 * lg + rr;
        const int tloc = row >> 1, r = row & 1;
        Zl[(tloc * 128 + n * 16 + lrow) * 8 + w * 2 + r] = f2bf(acc[n][rr]);
      }
    __syncthreads();

    const long gbase = ((long)bp * T_STEPS + tc * 8) * 128;  // chunk index
#pragma unroll
    for (int i = 0; i < 4; ++i) {
      const int q = tid + 256 * i;
      *(s16x8*)(Zp + (gbase + q) * 8) = *(const s16x8*)&Zl[q * 8];
    }
    __syncthreads();
  }
}

// ---------------------------------------------------------------------------
// Phase 2: the scan. K=128 (U only); gates init from prefetched Z chunks.
// ---------------------------------------------------------------------------
__global__ __launch_bounds__(NTHR, 2)
void lstm_z_kernel(const unsigned short* __restrict__ Zp,
                   const float* __restrict__ U,
                   const float* __restrict__ LW, const float* __restrict__ LB,
                   float* __restrict__ OUT) {
  __shared__ __align__(16) short Hb[2][ROWS * HSTR];
  __shared__ float Ys[256];
  __shared__ float Ps[8];

  const int tid  = threadIdx.x;
  const int lane = tid & 63;
  const int w    = tid >> 6;
  const int blk  = blockIdx.x;
  const int lrow = lane & 15;
  const int lg   = lane >> 4;

  // weights: gate n, cols n*128 + 16w + [0,16), K=128 (U)
  s16x8 bfr[4][4];
#pragma unroll
  for (int n = 0; n < 4; ++n) {
    const int col = n * HS + w * 16 + lrow;
#pragma unroll
    for (int kt = 0; kt < 4; ++kt) {
#pragma unroll
      for (int j = 0; j < 8; ++j) {
        const int k = kt * 32 + (lg << 3) + j;
        bfr[n][kt][j] = (short)f2bf(U[k * NG + col]);
      }
    }
  }

  // Z chunk stream: chunk c = w*16 + lrow of block blk
  const unsigned short* zbase = Zp + (((long)blk * T_STEPS) * 128 + w * 16 + lrow) * 8;
  s16x8 za = *(const s16x8*)(zbase);          // t=0
  s16x8 zb = *(const s16x8*)(zbase + 1024);   // t=1

  s16x8 afr[4];
  const s16x8 zer = {0, 0, 0, 0, 0, 0, 0, 0};
#pragma unroll
  for (int kt = 0; kt < 4; ++kt) afr[kt] = zer;  // h(0)=0

  float creg = 0.f;

  auto step = [&](int t, s16x8& zc) {
    // gates = Z(t) + h @ U  (acc C-init from the Z chunk)
    f32x4 acc[4];
#pragma unroll
    for (int n = 0; n < 4; ++n) {
      acc[n][0] = bf2f((unsigned short)zc[2 * n]);
      acc[n][1] = bf2f((unsigned short)zc[2 * n + 1]);
      acc[n][2] = 0.f; acc[n][3] = 0.f;
    }
    // refill this buffer with Z(t+2) (consumed again 2 steps from now)
    const int tn = (t + 2 < T_STEPS) ? t + 2 : T_STEPS - 1;
    zc = *(const s16x8*)(zbase + (long)tn * 1024);

#pragma unroll
    for (int kt = 0; kt < 4; ++kt)
#pragma unroll
      for (int n = 0; n < 4; ++n)
        acc[n] = __builtin_amdgcn_mfma_f32_16x16x32_bf16(afr[kt], bfr[n][kt], acc[n], 0, 0, 0);

    // row1 -> lanes 16..31 via swizzle; one (row,col) per lane (lanes<32)
    float v[4];
#pragma unroll
    for (int n = 0; n < 4; ++n) {
      const float s = __int_as_float(
          __builtin_amdgcn_ds_swizzle(__float_as_int(acc[n][1]), 0x401F));
      v[n] = (lane & 16) ? s : acc[n][0];
    }
    const float iv = sigm(v[0]), fv = sigm(v[1]);
    const float gv = tanhfast(v[2]), ov = sigm(v[3]);
    creg = fv * creg + iv * gv;
    const float hv = ov * tanhfast(creg);

    if (lane < 32) {
      const int col = w * 16 + lrow;
      const int r   = lg & 1;
      if (t < T_STEPS - 1) {
        Hb[(t + 1) & 1][r * HSTR + col] = (short)f2bf(hv);
      } else {
        const int row = blk * ROWS + r;
        OUT[512 + row * HS + col]   = hv;
        OUT[66048 + row * HS + col] = creg;
        Ys[r * HS + col] = LW[col] * hv;
      }
    }
    __syncthreads();

    if (t < T_STEPS - 1 && lrow < ROWS) {
      const short* hb = &Hb[(t + 1) & 1][lrow * HSTR];
      afr[0] = *(const s16x8*)&hb[(lg << 3)];
      afr[1] = *(const s16x8*)&hb[32 + (lg << 3)];
      afr[2] = *(const s16x8*)&hb[64 + (lg << 3)];
      afr[3] = *(const s16x8*)&hb[96 + (lg << 3)];
    }
  };

#pragma unroll 1
  for (int t = 0; t < T_STEPS; t += 2) {
    step(t, za);
    step(t + 1, zb);
  }

  // y = h @ linear_w.T + b
  if (tid < 8) {
    const int r = tid >> 2, seg = tid & 3;
    float s = 0.f;
#pragma unroll 8
    for (int j = 0; j < 32; ++j) s += Ys[r * 128 + seg * 32 + j];
    Ps[tid] = s;
  }
  __syncthreads();
  if (tid < ROWS) {
    OUT[blk * ROWS + tid] = LB[0] + Ps[tid * 4] + Ps[tid * 4 + 1]
                                  + Ps[tid * 4 + 2] + Ps[tid * 4 + 3];
  }
}

// ---------------------------------------------------------------------------
// Fallback (ws too small for Z): R3 kernel, in-loop x@W (K=192).
// ---------------------------------------------------------------------------
__global__ __launch_bounds__(NTHR, 2)
void lstm_fb_kernel(const float* __restrict__ X, const float* __restrict__ W,
                    const float* __restrict__ U, const float* __restrict__ B,
                    const float* __restrict__ LW, const float* __restrict__ LB,
                    float* __restrict__ OUT) {
  __shared__ __align__(16) short Hb[2][ROWS * HSTR];
  __shared__ __align__(16) short Xs[2][ROWS][IN_DIM];
  __shared__ float Ys[256];
  __shared__ float Ps[8];

  const int tid  = threadIdx.x;
  const int lane = tid & 63;
  const int w    = tid >> 6;
  const int blk  = blockIdx.x;
  const int lrow = lane & 15;
  const int lg   = lane >> 4;

  s16x8 bfr[4][6];
#pragma unroll
  for (int n = 0; n < 4; ++n) {
    const int col = n * HS + w * 16 + lrow;
#pragma unroll
    for (int kt = 0; kt < 6; ++kt) {
#pragma unroll
      for (int j = 0; j < 8; ++j) {
        const int k = kt * 32 + (lg << 3) + j;
        const float v = (k < HS) ? U[k * NG + col] : W[(k - HS) * NG + col];
        bfr[n][kt][j] = (short)f2bf(v);
      }
    }
  }
  float biasr[4];
#pragma unroll
  for (int n = 0; n < 4; ++n) biasr[n] = B[n * HS + w * 16 + lrow];

  float xa = 0.f, xb = 0.f;
  const float* xg = nullptr;
  if (w < ROWS) {
    xg = X + ((long)(blk * ROWS + w) * T_STEPS) * IN_DIM + lane;
    Xs[0][w][lane] = (short)f2bf(xg[0]);
    xa = xg[IN_DIM];
    xb = xg[2 * IN_DIM];
  }
  __syncthreads();

  s16x8 afr[6];
  const s16x8 zer = {0, 0, 0, 0, 0, 0, 0, 0};
#pragma unroll
  for (int kt = 0; kt < 6; ++kt) afr[kt] = zer;
  if (lrow < ROWS) {
    afr[4] = *(const s16x8*)&Xs[0][lrow][lg << 3];
    afr[5] = *(const s16x8*)&Xs[0][lrow][32 + (lg << 3)];
  }

  float creg = 0.f;

#pragma unroll 1
  for (int t = 0; t < T_STEPS; ++t) {
    if (w < ROWS) {
      Xs[(t + 1) & 1][w][lane] = (short)f2bf(xa);
      xa = xb;
      const int tsrc = (t + 3 < T_STEPS) ? t + 3 : T_STEPS - 1;
      xb = xg[(long)tsrc * IN_DIM];
    }

    f32x4 acc[4];
#pragma unroll
    for (int n = 0; n < 4; ++n) {
      acc[n][0] = biasr[n]; acc[n][1] = biasr[n];
      acc[n][2] = biasr[n]; acc[n][3] = biasr[n];
    }
    const int kord[6] = {4, 5, 0, 1, 2, 3};
#pragma unroll
    for (int kk = 0; kk < 6; ++kk) {
      const int kt = kord[kk];
#pragma unroll
      for (int n = 0; n < 4; ++n)
        acc[n] = __builtin_amdgcn_mfma_f32_16x16x32_bf16(afr[kt], bfr[n][kt], acc[n], 0, 0, 0);
    }

    float v[4];
#pragma unroll
    for (int n = 0; n < 4; ++n) {
      const float s = __int_as_float(
          __builtin_amdgcn_ds_swizzle(__float_as_int(acc[n][1]), 0x401F));
      v[n] = (lane & 16) ? s : acc[n][0];
    }
    const float iv = sigm(v[0]), fv = sigm(v[1]);
    const float gv = tanhfast(v[2]), ov = sigm(v[3]);
    creg = fv * creg + iv * gv;
    const float hv = ov * tanhfast(creg);

    if (lane < 32) {
      const int col = w * 16 + lrow;
      const int r   = lg & 1;
      if (t < T_STEPS - 1) {
        Hb[(t + 1) & 1][r * HSTR + col] = (short)f2bf(hv);
      } else {
        const int row = blk * ROWS + r;
        OUT[512 + row * HS + col]   = hv;
        OUT[66048 + row * HS + col] = creg;
        Ys[r * HS + col] = LW[col] * hv;
      }
    }
    __syncthreads();

    if (t < T_STEPS - 1) {
      if (lrow < ROWS) {
        const int p = (t + 1) & 1;
        afr[4] = *(const s16x8*)&Xs[p][lrow][lg << 3];
        afr[5] = *(const s16x8*)&Xs[p][lrow][32 + (lg << 3)];
        const short* hb = &Hb[p][lrow * HSTR];
        afr[0] = *(const s16x8*)&hb[(lg << 3)];
        afr[1] = *(const s16x8*)&hb[32 + (lg << 3)];
        afr[2] = *(const s16x8*)&hb[64 + (lg << 3)];
        afr[3] = *(const s16x8*)&hb[96 + (lg << 3)];
      }
    }
  }

  if (tid < 8) {
    const int r = tid >> 2, seg = tid & 3;
    float s = 0.f;
#pragma unroll 8
    for (int j = 0; j < 32; ++j) s += Ys[r * 128 + seg * 32 + j];
    Ps[tid] = s;
  }
  __syncthreads();
  if (tid < ROWS) {
    OUT[blk * ROWS + tid] = LB[0] + Ps[tid * 4] + Ps[tid * 4 + 1]
                                  + Ps[tid * 4 + 2] + Ps[tid * 4 + 3];
  }
}

extern "C" void kernel_launch(void* const* d_in, const int* in_sizes, int n_in,
                              void* d_out, int out_size, void* d_ws, size_t ws_size,
                              hipStream_t stream) {
  const float* X  = (const float*)d_in[0];
  const float* W  = (const float*)d_in[1];
  const float* U  = (const float*)d_in[2];
  const float* B  = (const float*)d_in[3];
  const float* LW = (const float*)d_in[4];
  const float* LB = (const float*)d_in[5];
  const size_t ZBYTES = (size_t)512 * 2048 * 512 * 2;  // 1 GiB
  if (ws_size >= ZBYTES) {
    unsigned short* Zp = (unsigned short*)d_ws;
    zgemm_kernel<<<dim3(256), dim3(256), 0, stream>>>(X, W, B, Zp);
    lstm_z_kernel<<<dim3(NBLK), dim3(NTHR), 0, stream>>>(Zp, U, LW, LB, (float*)d_out);
  } else {
    lstm_fb_kernel<<<dim3(NBLK), dim3(NTHR), 0, stream>>>(X, W, U, B, LW, LB, (float*)d_out);
  }
}

// Round 5
// 1372.095 us; speedup vs baseline: 1.5538x; 1.0130x over previous
//
#include <hip/hip_runtime.h>

// LSTM BS=512, T=2048, IN=64, HS=128.  Single fused persistent kernel:
// 256 blocks x 2 batch rows, 8 waves. Every CH=64 steps, a dense chunk-GEMM
// computes Z = x@W + bias for the next 64 timesteps into LDS (scan-native
// layout); the 64 scan steps then do only K=128 (U*h) MFMAs with acc
// initialized from a broadcast ds_read of Z. No workspace, no HBM Z traffic.

#define T_STEPS 2048
#define IN_DIM 64
#define HS 128
#define NG 512
#define ROWS 2
#define NBLK 256
#define NTHR 512
#define HSTR 144
#define CH 64
#define NCH (T_STEPS / CH)

typedef float f32x4 __attribute__((ext_vector_type(4)));
typedef short s16x8 __attribute__((ext_vector_type(8)));

__device__ __forceinline__ unsigned short f2bf(float f) {
  unsigned u = __float_as_uint(f);
  return (unsigned short)((u + 0x7fffu + ((u >> 16) & 1u)) >> 16);  // RNE
}
__device__ __forceinline__ float bf2f(unsigned short s) {
  return __int_as_float(((int)s) << 16);
}
__device__ __forceinline__ float rcpf(float x) { return __builtin_amdgcn_rcpf(x); }
__device__ __forceinline__ float sigm(float x) { return rcpf(1.0f + __expf(-x)); }
__device__ __forceinline__ float tanhfast(float x) {
  return 1.0f - 2.0f * rcpf(__expf(2.0f * x) + 1.0f);  // exact at +-inf
}

__global__ __launch_bounds__(NTHR, 1)
void lstm_fused(const float* __restrict__ X, const float* __restrict__ W,
                const float* __restrict__ U, const float* __restrict__ B,
                const float* __restrict__ LW, const float* __restrict__ LB,
                float* __restrict__ OUT) {
  // Zc cell (tl, col): 8 shorts = [r0:n0..n3 | r1:n0..n3], 16B aligned
  __shared__ __align__(16) short Zc[CH * 128 * 8];     // 128 KB
  __shared__ __align__(16) short Hb[2][ROWS * HSTR];   // h double buffer
  __shared__ float Ys[256];
  __shared__ float Ps[8];

  const int tid  = threadIdx.x;
  const int lane = tid & 63;
  const int w    = tid >> 6;
  const int blk  = blockIdx.x;
  const int lrow = lane & 15;
  const int lg   = lane >> 4;
  const int col8 = (w * 16 + lrow) * 8;   // Zc column offset (shorts)

  // ---- persistent weight fragments: wave w owns col p = n*128 + 16w + lrow
  // of gate n (n-tile n).  B-frag: B[k][p], k = kt*32 + 8*lg + j.
  s16x8 bfrU[4][4];   // K=128 (U)
  s16x8 bfrW[4][2];   // K=64  (W)
  float biasg[4];
#pragma unroll
  for (int n = 0; n < 4; ++n) {
    const int p = n * HS + w * 16 + lrow;
#pragma unroll
    for (int kt = 0; kt < 4; ++kt)
#pragma unroll
      for (int j = 0; j < 8; ++j)
        bfrU[n][kt][j] = (short)f2bf(U[(kt * 32 + (lg << 3) + j) * NG + p]);
#pragma unroll
    for (int kt = 0; kt < 2; ++kt)
#pragma unroll
      for (int j = 0; j < 8; ++j)
        bfrW[n][kt][j] = (short)f2bf(W[(kt * 32 + (lg << 3) + j) * NG + p]);
    biasg[n] = B[p];
  }

  // ---- chunk-GEMM A-tile source: lane -> batch row (lrow&1), t-row (lrow>>1)
  const float* xbA = X + ((long)(blk * ROWS + (lrow & 1)) * T_STEPS + (lrow >> 1)) * IN_DIM + (lg << 3);

  // prefetch chunk 0, m-tile 0
  f32x4 qp0 = *(const f32x4*)(xbA);
  f32x4 qp1 = *(const f32x4*)(xbA + 4);
  f32x4 qp2 = *(const f32x4*)(xbA + 32);
  f32x4 qp3 = *(const f32x4*)(xbA + 36);

  s16x8 afr[4];
  const s16x8 zer = {0, 0, 0, 0, 0, 0, 0, 0};
#pragma unroll
  for (int kt = 0; kt < 4; ++kt) afr[kt] = zer;  // h(0) = 0

  float creg = 0.f, hreg = 0.f;

#pragma unroll 1
  for (int c = 0; c < NCH; ++c) {
    // ================= chunk GEMM: Zc = x@W + bias for t in [64c, 64c+64) ==
    {
      const float* xc = xbA + (long)c * CH * IN_DIM;
      f32x4 q0 = qp0, q1 = qp1, q2 = qp2, q3 = qp3;
#pragma unroll
      for (int mt = 0; mt < 8; ++mt) {
        f32x4 n0, n1, n2, n3;
        if (mt < 7) {
          const float* p = xc + (mt + 1) * 8 * IN_DIM;
          n0 = *(const f32x4*)(p);      n1 = *(const f32x4*)(p + 4);
          n2 = *(const f32x4*)(p + 32); n3 = *(const f32x4*)(p + 36);
        }
        s16x8 a0, a1;
#pragma unroll
        for (int j = 0; j < 4; ++j) {
          a0[j] = (short)f2bf(q0[j]); a0[4 + j] = (short)f2bf(q1[j]);
          a1[j] = (short)f2bf(q2[j]); a1[4 + j] = (short)f2bf(q3[j]);
        }
        f32x4 ac[4];
#pragma unroll
        for (int n = 0; n < 4; ++n) {
          ac[n][0] = biasg[n]; ac[n][1] = biasg[n];
          ac[n][2] = biasg[n]; ac[n][3] = biasg[n];
        }
#pragma unroll
        for (int n = 0; n < 4; ++n)
          ac[n] = __builtin_amdgcn_mfma_f32_16x16x32_bf16(a0, bfrW[n][0], ac[n], 0, 0, 0);
#pragma unroll
        for (int n = 0; n < 4; ++n)
          ac[n] = __builtin_amdgcn_mfma_f32_16x16x32_bf16(a1, bfrW[n][1], ac[n], 0, 0, 0);

        // D row d=4lg+rr -> m-row 16mt+d -> (tl = 8mt+2lg+(rr>>1), r = rr&1)
        s16x8 z0, z1;
#pragma unroll
        for (int n = 0; n < 4; ++n) {
          z0[n] = (short)f2bf(ac[n][0]); z0[4 + n] = (short)f2bf(ac[n][1]);
          z1[n] = (short)f2bf(ac[n][2]); z1[4 + n] = (short)f2bf(ac[n][3]);
        }
        const int tl0 = mt * 8 + 2 * lg;
        *(s16x8*)&Zc[tl0 * 1024 + col8]       = z0;
        *(s16x8*)&Zc[(tl0 + 1) * 1024 + col8] = z1;
        q0 = n0; q1 = n1; q2 = n2; q3 = n3;
      }
      // prefetch next chunk's m-tile 0 (clamped; lands during scan steps)
      const float* pn = xbA + (long)((c + 1 < NCH) ? c + 1 : c) * CH * IN_DIM;
      qp0 = *(const f32x4*)(pn);      qp1 = *(const f32x4*)(pn + 4);
      qp2 = *(const f32x4*)(pn + 32); qp3 = *(const f32x4*)(pn + 36);
    }
    __syncthreads();

    // ================= 64 scan steps =======================================
#pragma unroll 1
    for (int tl = 0; tl < CH; ++tl) {
      const int t = (c << 6) + tl;

      const s16x8 zc = *(const s16x8*)&Zc[tl * 1024 + col8];  // broadcast read
      f32x4 acc[4];
#pragma unroll
      for (int n = 0; n < 4; ++n) {
        acc[n][0] = bf2f((unsigned short)zc[n]);
        acc[n][1] = bf2f((unsigned short)zc[4 + n]);
        acc[n][2] = 0.f; acc[n][3] = 0.f;
      }

      __builtin_amdgcn_s_setprio(1);
#pragma unroll
      for (int kt = 0; kt < 4; ++kt)
        acc[0] = __builtin_amdgcn_mfma_f32_16x16x32_bf16(afr[kt], bfrU[0][kt], acc[0], 0, 0, 0);
#pragma unroll
      for (int kt = 0; kt < 4; ++kt)
        acc[2] = __builtin_amdgcn_mfma_f32_16x16x32_bf16(afr[kt], bfrU[2][kt], acc[2], 0, 0, 0);
#pragma unroll
      for (int kt = 0; kt < 4; ++kt)
        acc[1] = __builtin_amdgcn_mfma_f32_16x16x32_bf16(afr[kt], bfrU[1][kt], acc[1], 0, 0, 0);
#pragma unroll
      for (int kt = 0; kt < 4; ++kt)
        acc[3] = __builtin_amdgcn_mfma_f32_16x16x32_bf16(afr[kt], bfrU[3][kt], acc[3], 0, 0, 0);
      __builtin_amdgcn_s_setprio(0);

      // i,g first (their accs finish first), f,o while i*g computes
      const float s0 = __int_as_float(
          __builtin_amdgcn_ds_swizzle(__float_as_int(acc[0][1]), 0x401F));
      const float s2 = __int_as_float(
          __builtin_amdgcn_ds_swizzle(__float_as_int(acc[2][1]), 0x401F));
      const float v0 = (lane & 16) ? s0 : acc[0][0];
      const float v2 = (lane & 16) ? s2 : acc[2][0];
      const float iv = sigm(v0), gv = tanhfast(v2);
      const float pg = iv * gv;
      const float s1 = __int_as_float(
          __builtin_amdgcn_ds_swizzle(__float_as_int(acc[1][1]), 0x401F));
      const float s3 = __int_as_float(
          __builtin_amdgcn_ds_swizzle(__float_as_int(acc[3][1]), 0x401F));
      const float v1 = (lane & 16) ? s1 : acc[1][0];
      const float v3 = (lane & 16) ? s3 : acc[3][0];
      const float fv = sigm(v1), ov = sigm(v3);
      creg = fv * creg + pg;
      hreg = ov * tanhfast(creg);

      if (lane < 32) {
        const int col = w * 16 + lrow;
        const int r   = lg & 1;
        if (t < T_STEPS - 1) {
          Hb[(t + 1) & 1][r * HSTR + col] = (short)f2bf(hreg);
        } else {
          const int row = blk * ROWS + r;
          OUT[512 + row * HS + col]   = hreg;   // h_t
          OUT[66048 + row * HS + col] = creg;   // c_t
          Ys[r * HS + col] = LW[col] * hreg;    // y partials
        }
      }
      __syncthreads();

      if (t < T_STEPS - 1 && lrow < ROWS) {
        const short* hb = &Hb[(t + 1) & 1][lrow * HSTR];
        afr[0] = *(const s16x8*)&hb[(lg << 3)];
        afr[1] = *(const s16x8*)&hb[32 + (lg << 3)];
        afr[2] = *(const s16x8*)&hb[64 + (lg << 3)];
        afr[3] = *(const s16x8*)&hb[96 + (lg << 3)];
      }
    }
  }

  // ---- y = h @ linear_w.T + b ----
  if (tid < 8) {
    const int r = tid >> 2, seg = tid & 3;
    float s = 0.f;
#pragma unroll 8
    for (int j = 0; j < 32; ++j) s += Ys[r * 128 + seg * 32 + j];
    Ps[tid] = s;
  }
  __syncthreads();
  if (tid < ROWS) {
    OUT[blk * ROWS + tid] = LB[0] + Ps[tid * 4] + Ps[tid * 4 + 1]
                                  + Ps[tid * 4 + 2] + Ps[tid * 4 + 3];
  }
}

extern "C" void kernel_launch(void* const* d_in, const int* in_sizes, int n_in,
                              void* d_out, int out_size, void* d_ws, size_t ws_size,
                              hipStream_t stream) {
  const float* X  = (const float*)d_in[0];
  const float* W  = (const float*)d_in[1];
  const float* U  = (const float*)d_in[2];
  const float* B  = (const float*)d_in[3];
  const float* LW = (const float*)d_in[4];
  const float* LB = (const float*)d_in[5];
  lstm_fused<<<dim3(NBLK), dim3(NTHR), 0, stream>>>(X, W, U, B, LW, LB, (float*)d_out);
}